// Round 1
// baseline (675.719 us; speedup 1.0000x reference)
//
#include <hip/hip_runtime.h>
#include <hip/hip_bf16.h>

#define DIM      512
#define NSTEPS   16

// d_out offsets (f32 elements)
#define OFF_XF   0
#define OFF_VF   2097152
#define OFF_POS  4194304
#define OFF_VEL  39845888
#define OFF_GZ   75497472
#define OFF_CONV 75497489
#define SLAB     2097152

// d_ws layout (bytes)
#define WS_WV 0
#define WS_W1 524288
#define WS_W2 1048576
#define WS_GZ 1572864   // 17 floats of gray-zone partial sums

typedef __attribute__((ext_vector_type(8))) short short8v;  // 8 bf16 = 4 VGPR
typedef __attribute__((ext_vector_type(4))) float f32x4;

__device__ __forceinline__ unsigned short f2bf(float f) {
  union { float f; unsigned u; } a; a.f = f;
  return (unsigned short)((a.u + 0x7FFFu + ((a.u >> 16) & 1u)) >> 16);
}

__device__ __forceinline__ float tanh_fast(float x) {
  float e = __expf(2.0f * x);           // large +x -> inf -> 1; large -x -> 0 -> -1
  return 1.0f - 2.0f / (e + 1.0f);
}

// swizzled bf16 store into [32][512] LDS tile (row stride 1024 B, XOR bits 4-6)
__device__ __forceinline__ void st_bf(unsigned short* lds, int r, int c, float f) {
  int byte = (c << 1) ^ ((r & 7) << 4);
  *(unsigned short*)((char*)lds + (r << 10) + byte) = f2bf(f);
}

// ---- prep: f32 weights -> bf16 fragment-linear layout in ws; zero gz sums ----
// frag layout: elem j of lane L for (ntile, ktile):
//   W[nt*16 + (L&15)][kt*32 + (L>>4)*8 + j]  stored at ((nt*16+kt)*64+L)*8 + j
__global__ void prep_kernel(const float* __restrict__ Wv,
                            const float* __restrict__ W1,
                            const float* __restrict__ W2,
                            unsigned short* __restrict__ ws) {
  int t = blockIdx.x * 256 + threadIdx.x;          // 3*32*16*64 = 98304 threads
  if (t < 32) ((float*)(ws + WS_GZ / 2))[t] = 0.0f;
  int lane = t & 63, kt = (t >> 6) & 15, nt = (t >> 10) & 31, mat = t >> 15;
  const float* W = (mat == 0) ? Wv : (mat == 1) ? W1 : W2;
  int stride = (mat == 1) ? 1024 : 512;            // W1 is (512,1024); use cols [0,512)
  unsigned short* o = ws + (mat == 0 ? WS_WV / 2 : mat == 1 ? WS_W1 / 2 : WS_W2 / 2);
  int row = nt * 16 + (lane & 15);
  int col = kt * 32 + (lane >> 4) * 8;
  const float* src = W + row * stride + col;
  short8v v;
#pragma unroll
  for (int j = 0; j < 8; ++j) v[j] = (short)f2bf(src[j]);
  *(short8v*)(o + (((nt * 16 + kt) * 64 + lane) * 8)) = v;
}

// ---- main persistent kernel: 128 blocks x 512 thr, 32 rows/block, 16 steps ----
#define GEMM_512(WB) do {                                                     \
    const short8v* __wv = (const short8v*)(WB);                               \
    _Pragma("unroll")                                                         \
    for (int nt_ = 0; nt_ < 8; ++nt_) acc[nt_] = (f32x4){0.f, 0.f, 0.f, 0.f};\
    _Pragma("unroll 2")                                                       \
    for (int kt_ = 0; kt_ < 16; ++kt_) {                                      \
      short8v a_ = *(const short8v*)(aptr + ((kt_ * 64 + acol0) ^ aswz));     \
      short8v b_[8];                                                          \
      _Pragma("unroll")                                                       \
      for (int nt_ = 0; nt_ < 8; ++nt_)                                       \
        b_[nt_] = __wv[((ng8 + nt_) * 16 + kt_) * 64 + lane];                 \
      _Pragma("unroll")                                                       \
      for (int nt_ = 0; nt_ < 8; ++nt_)                                       \
        acc[nt_] = __builtin_amdgcn_mfma_f32_16x16x32_bf16(a_, b_[nt_],       \
                                                           acc[nt_], 0, 0, 0);\
    }                                                                         \
  } while (0)

__launch_bounds__(512)
__global__ void main_kernel(const float* __restrict__ x0,
                            const float* __restrict__ noise,
                            const float* __restrict__ bv,
                            const float* __restrict__ b1,
                            const float* __restrict__ b2,
                            const float* __restrict__ Wg1,
                            const float* __restrict__ bg1,
                            const float* __restrict__ Wg2,
                            const float* __restrict__ bg2,
                            const float* __restrict__ rdecay,
                            const float* __restrict__ rdt,
                            const float* __restrict__ rspring,
                            const float* __restrict__ rthr,
                            const unsigned short* __restrict__ ws,
                            float* __restrict__ gzsum,
                            float* __restrict__ out) {
  __shared__ unsigned short a_lds[32 * 512];  // x (then h) as bf16, swizzled
  __shared__ float gz_p[32];
  __shared__ float gate_lds[32];

  const int tid  = threadIdx.x;
  const int lane = tid & 63;
  const int w    = tid >> 6;       // 8 waves
  const int mt   = w & 1;          // M-tile (pair waves mt=0/1 share B frags -> L1 reuse)
  const int ng   = w >> 1;         // n-group: 128 cols
  const int ng8  = ng * 8;
  const int lg   = lane >> 4;
  const int li   = lane & 15;
  const int base = blockIdx.x * 32;

  const float decay  = fminf(fmaxf(rdecay[0], 0.5f), 0.99f);
  const float dt     = fminf(fmaxf(rdt[0], 0.01f), 0.5f);
  const float spring = fabsf(rspring[0]) + 0.01f;

  // A-frag addressing constants
  const char* aptr = (const char*)a_lds + (mt * 16 + li) * 1024;
  const int acol0 = lg * 16;
  const int aswz  = (li & 7) << 4;

  int colv[8], rowv[4], rg[4];
  float b1c[8], b2c[8], bvc[8];
#pragma unroll
  for (int nt = 0; nt < 8; ++nt) {
    colv[nt] = ng * 128 + nt * 16 + li;
    b1c[nt] = b1[colv[nt]]; b2c[nt] = b2[colv[nt]]; bvc[nt] = bv[colv[nt]];
  }
#pragma unroll
  for (int j = 0; j < 4; ++j) { rowv[j] = mt * 16 + lg * 4 + j; rg[j] = (base + rowv[j]) * DIM; }

  // ---- prologue: stage x0 into LDS (bf16) + load f32 x state ----
  for (int i = tid; i < 32 * DIM; i += 512) {
    int r = i >> 9, c = i & 511;
    st_bf(a_lds, r, c, x0[(base + r) * DIM + c]);
  }
  float x[8][4], v[8][4];
#pragma unroll
  for (int nt = 0; nt < 8; ++nt)
#pragma unroll
    for (int j = 0; j < 4; ++j) x[nt][j] = x0[rg[j] + colv[nt]];
  __syncthreads();

  f32x4 acc[8];
  // v0 = x0 @ Wv^T + bv
  GEMM_512(ws + WS_WV / 2);
#pragma unroll
  for (int nt = 0; nt < 8; ++nt)
#pragma unroll
    for (int j = 0; j < 4; ++j) {
      v[nt][j] = acc[nt][j] + bvc[nt];
      out[OFF_VEL + rg[j] + colv[nt]] = v[nt][j];   // velocities[0]
    }

  // ---- 16 steps ----
  for (int t = 0; t < NSTEPS; ++t) {
    __syncthreads();                       // prev GEMM2 done reading a_lds / gate
    if (tid < 32) gz_p[tid] = 0.0f;
    if (t > 0) {
#pragma unroll
      for (int nt = 0; nt < 8; ++nt)
#pragma unroll
        for (int j = 0; j < 4; ++j) st_bf(a_lds, rowv[j], colv[nt], x[nt][j]);
    }
    __syncthreads();                       // x staged, gz_p zeroed

    // per-row ||v||^2 partials: reduce over 16 lanes, atomic over 4 n-groups
#pragma unroll
    for (int j = 0; j < 4; ++j) {
      float s = 0.f;
#pragma unroll
      for (int nt = 0; nt < 8; ++nt) s += v[nt][j] * v[nt][j];
      s += __shfl_xor(s, 1); s += __shfl_xor(s, 2);
      s += __shfl_xor(s, 4); s += __shfl_xor(s, 8);
      if (li == 0) atomicAdd(&gz_p[rowv[j]], s);
    }
    __syncthreads();                       // gz_p complete

    if (tid < 32) {                        // gate MLP + gray-zone partial
      float g = sqrtf(gz_p[tid]);
      float z = bg2[0];
#pragma unroll
      for (int k = 0; k < 32; ++k) {
        float a = fmaxf(fmaf(g, Wg1[k], bg1[k]), 0.0f);
        z = fmaf(Wg2[k], a, z);
      }
      gate_lds[tid] = 1.0f / (1.0f + __expf(-z));
      float bs = g;
      bs += __shfl_xor(bs, 1); bs += __shfl_xor(bs, 2); bs += __shfl_xor(bs, 4);
      bs += __shfl_xor(bs, 8); bs += __shfl_xor(bs, 16);
      if (tid == 0) {
        atomicAdd(&gzsum[t + 1], bs);
        if (t == 0) atomicAdd(&gzsum[0], bs);   // gray_zones[0] == gray_zones[1]
      }
    }

    // GEMM1: z1 = x @ W1a^T   (evidence half is zeros -> only W1[:, :512])
    GEMM_512(ws + WS_W1 / 2);
    __syncthreads();                       // all waves done reading x from a_lds
#pragma unroll
    for (int nt = 0; nt < 8; ++nt)
#pragma unroll
      for (int j = 0; j < 4; ++j)
        st_bf(a_lds, rowv[j], colv[nt], tanh_fast(acc[nt][j] + b1c[nt]));
    __syncthreads();                       // h staged

    // prefetch noise under GEMM2
    float nz[8][4];
    const float* np = noise + (size_t)t * (4096 * DIM);
#pragma unroll
    for (int nt = 0; nt < 8; ++nt)
#pragma unroll
      for (int j = 0; j < 4; ++j) nz[nt][j] = np[rg[j] + colv[nt]];

    // GEMM2: f = h @ W2^T
    GEMM_512(ws + WS_W2 / 2);

    // update + stream outputs
    float* pos = out + OFF_POS + (size_t)(t + 1) * SLAB;
    float* vel = out + OFF_VEL + (size_t)(t + 1) * SLAB;
#pragma unroll
    for (int j = 0; j < 4; ++j) {
      float g = gate_lds[rowv[j]];
#pragma unroll
      for (int nt = 0; nt < 8; ++nt) {
        float force = spring * (acc[nt][j] + b2c[nt]);
        float vn = fmaf(decay, v[nt][j], force) + nz[nt][j] * g * 0.1f;
        v[nt][j] = vn;
        x[nt][j] = fmaf(dt, vn, x[nt][j]);
        int gi = rg[j] + colv[nt];
        pos[gi] = x[nt][j];
        vel[gi] = vn;
        if (t == NSTEPS - 1) { out[OFF_XF + gi] = x[nt][j]; out[OFF_VF + gi] = vn; }
      }
    }
  }

  // ---- converged = ||v_f|| < threshold ----
  if (tid < 32) gz_p[tid] = 0.0f;
  __syncthreads();
#pragma unroll
  for (int j = 0; j < 4; ++j) {
    float s = 0.f;
#pragma unroll
    for (int nt = 0; nt < 8; ++nt) s += v[nt][j] * v[nt][j];
    s += __shfl_xor(s, 1); s += __shfl_xor(s, 2);
    s += __shfl_xor(s, 4); s += __shfl_xor(s, 8);
    if (li == 0) atomicAdd(&gz_p[rowv[j]], s);
  }
  __syncthreads();
  if (tid < 32) {
    float thr = fabsf(rthr[0]) + 1e-4f;
    out[OFF_CONV + base + tid] = (sqrtf(gz_p[tid]) < thr) ? 1.0f : 0.0f;
  }
}

__global__ void finalize_kernel(const float* __restrict__ gzsum,
                                float* __restrict__ out) {
  int t = threadIdx.x;
  if (t < 17) out[OFF_GZ + t] = gzsum[t] * (1.0f / 4096.0f);
}

extern "C" void kernel_launch(void* const* d_in, const int* in_sizes, int n_in,
                              void* d_out, int out_size, void* d_ws, size_t ws_size,
                              hipStream_t stream) {
  const float* x0     = (const float*)d_in[0];
  const float* noise  = (const float*)d_in[1];
  const float* Wv     = (const float*)d_in[2];
  const float* bv     = (const float*)d_in[3];
  const float* W1     = (const float*)d_in[4];
  const float* b1     = (const float*)d_in[5];
  const float* W2     = (const float*)d_in[6];
  const float* b2     = (const float*)d_in[7];
  const float* Wg1    = (const float*)d_in[8];
  const float* bg1    = (const float*)d_in[9];
  const float* Wg2    = (const float*)d_in[10];
  const float* bg2    = (const float*)d_in[11];
  const float* rdec   = (const float*)d_in[12];
  const float* rdt    = (const float*)d_in[13];
  const float* rspr   = (const float*)d_in[14];
  const float* rthr   = (const float*)d_in[15];
  unsigned short* ws  = (unsigned short*)d_ws;
  float* gz           = (float*)((char*)d_ws + WS_GZ);
  float* out          = (float*)d_out;

  // positions[0] = initial_state
  hipMemcpyAsync(out + OFF_POS, x0, (size_t)4096 * DIM * sizeof(float),
                 hipMemcpyDeviceToDevice, stream);
  prep_kernel<<<384, 256, 0, stream>>>(Wv, W1, W2, ws);
  main_kernel<<<128, 512, 0, stream>>>(x0, noise, bv, b1, b2, Wg1, bg1, Wg2, bg2,
                                       rdec, rdt, rspr, rthr, ws, gz, out);
  finalize_kernel<<<1, 32, 0, stream>>>(gz, out);
}